// Round 7
// baseline (146.956 us; speedup 1.0000x reference)
//
#include <hip/hip_runtime.h>
#include <math.h>

typedef unsigned short u16;
typedef unsigned int u32;
typedef __bf16 bf16x8 __attribute__((ext_vector_type(8)));
typedef float f32x4 __attribute__((ext_vector_type(4)));

__device__ __forceinline__ u16 f2b(float f) {
  u32 u = __builtin_bit_cast(u32, f);
  u32 r = (u + 0x7FFFu + ((u >> 16) & 1u)) >> 16;
  return (u16)r;
}

__device__ __forceinline__ float b2f(u16 b) {
  u32 u = ((u32)b) << 16;
  return __builtin_bit_cast(float, u);
}

__device__ __forceinline__ void glds16(const void* g, void* lds) {
  __builtin_amdgcn_global_load_lds(
      (const __attribute__((address_space(1))) void*)(void*)(const_cast<void*>(g)),
      (__attribute__((address_space(3))) void*)lds, 16, 0, 0);
}

// ---------------- prep kernels ----------------

__global__ __launch_bounds__(256) void castx(const float* __restrict__ x, u16* __restrict__ xb) {
  int idx = blockIdx.x * 256 + threadIdx.x;
  float4 v = ((const float4*)x)[idx];
  ushort4 o;
  o.x = f2b(v.x); o.y = f2b(v.y); o.z = f2b(v.z); o.w = f2b(v.w);
  ((ushort4*)xb)[idx] = o;
}

__global__ __launch_bounds__(256) void buildw(const float* __restrict__ Wq, const float* __restrict__ Wk,
                                              const float* __restrict__ Wv, const float* __restrict__ Wo,
                                              u16* __restrict__ WbigT, u16* __restrict__ WoT) {
  const float SCALE = 0.08838834764831845f;  // 1/sqrt(128)
  int row = blockIdx.x;  // 0..2055
  int t = threadIdx.x;
  if (row < 512) {
    for (int k = t; k < 512; k += 256) WbigT[row*512 + k] = f2b(Wq[k*512 + row] * SCALE);
  } else if (row < 1024) {
    int n = row - 512;
    for (int k = t; k < 512; k += 256) WbigT[row*512 + k] = f2b(Wk[k*512 + n]);
  } else if (row < 1536) {
    int n = row - 1024;
    for (int k = t; k < 512; k += 256) WbigT[row*512 + k] = f2b(Wv[k*512 + n]);
  } else if (row < 1544) {
    int rr = row - 1536 + 2040;
    for (int k = t; k < 512; k += 256) WbigT[rr*512 + k] = 0;
  } else {
    int n = row - 1544;
    for (int k = t; k < 512; k += 256) WoT[n*512 + k] = f2b(Wo[k*512 + n]);
  }
}

__global__ __launch_bounds__(256) void wpe_kernel(const float* __restrict__ Wq, const float* __restrict__ pew,
                                                  const float* __restrict__ peh, u16* __restrict__ WbigT) {
  int k = blockIdx.x;  // 0..511
  int t = threadIdx.x;
  __shared__ float wrow[512];
  for (int j = t; j < 512; j += 256) wrow[j] = Wq[k*512 + j];
  __syncthreads();
  if (t < 252) {
    int h = t / 63, r = t - h*63;
    float aw = 0.f, ah = 0.f;
    for (int d = 0; d < 128; d++) {
      float qv = wrow[h*128 + d];
      aw += qv * pew[d*63 + r];
      ah += qv * peh[d*63 + r];
    }
    const float SCALE = 0.08838834764831845f;
    WbigT[(size_t)(1536 + t)*512 + k] = f2b(aw * SCALE);
    WbigT[(size_t)(1788 + t)*512 + k] = f2b(ah * SCALE);
  }
}

// ---------------- fused QKV+REL GEMM: 256x256 tile, 8 waves (2Mx4N), BK=64 (R5) ----------------
__global__ __launch_bounds__(512) void gemm256(
    const u16* __restrict__ A, const u16* __restrict__ Bt,
    u16* __restrict__ Qb, u16* __restrict__ Kb, u16* __restrict__ Vt,
    float* __restrict__ RELW, float* __restrict__ RELH)
{
  __shared__ char sm[131072];   // buf p at p*65536: A 32KB + B 32KB
  const int tid = threadIdx.x;
  const int w = tid >> 6, l = tid & 63, g = l >> 4, c = l & 15;
  const int bm = blockIdx.x, bn = blockIdx.y;
  const int wm = w >> 2, wn = w & 3;   // 2 x 4 waves

  f32x4 acc[8][4];
#pragma unroll
  for (int i = 0; i < 8; i++)
#pragma unroll
    for (int j = 0; j < 4; j++) acc[i][j] = f32x4{0.f, 0.f, 0.f, 0.f};

  const char* Ab = (const char*)A;
  const char* Bb = (const char*)Bt;
  const int rsub = l >> 3;
  const int csw = (((l & 7) ^ rsub) << 4);

#define G_STAGE(kb, p)                                                                    \
  {                                                                                       \
    char* As_ = sm + (p)*65536;                                                           \
    char* Bs_ = As_ + 32768;                                                              \
    const int kbyte = (kb) * 128;                                                         \
    _Pragma("unroll")                                                                     \
    for (int i2 = 0; i2 < 4; i2++) {                                                      \
      const int row = i2*64 + w*8 + rsub;                                                 \
      glds16(Ab + (size_t)(bm*256 + row) * 1024 + kbyte + csw, As_ + i2*8192 + w*1024);   \
      glds16(Bb + (size_t)(bn*256 + row) * 1024 + kbyte + csw, Bs_ + i2*8192 + w*1024);   \
    }                                                                                     \
  }

  G_STAGE(0, 0);
  G_STAGE(1, 1);

#pragma unroll
  for (int kb = 0; kb < 8; kb++) {
    const int p = kb & 1;
    if (kb < 7) { asm volatile("s_waitcnt vmcnt(8)" ::: "memory"); }
    else        { asm volatile("s_waitcnt vmcnt(0)" ::: "memory"); }
    __builtin_amdgcn_s_barrier();
    const char* As_ = sm + p*65536;
    const char* Bs_ = As_ + 32768;
#pragma unroll
    for (int ks = 0; ks < 2; ks++) {
      const int koff = (ks*64 + g*16) ^ ((c & 7) << 4);
      bf16x8 af[8], bfr[4];
#pragma unroll
      for (int mf = 0; mf < 8; mf++)
        af[mf] = *(const bf16x8*)(As_ + (wm*128 + mf*16 + c)*128 + koff);
#pragma unroll
      for (int nf = 0; nf < 4; nf++)
        bfr[nf] = *(const bf16x8*)(Bs_ + (wn*64 + nf*16 + c)*128 + koff);
#pragma unroll
      for (int mf = 0; mf < 8; mf++)
#pragma unroll
        for (int nf = 0; nf < 4; nf++)
          acc[mf][nf] = __builtin_amdgcn_mfma_f32_16x16x32_bf16(af[mf], bfr[nf], acc[mf][nf], 0, 0, 0);
    }
    __builtin_amdgcn_s_barrier();
    if (kb < 6) G_STAGE(kb + 2, p);
  }
#undef G_STAGE

  const int b = bm >> 2;
  const int iBase = (bm & 3) * 256;

  if (bn < 4) {
    u16* dst0 = (bn < 2) ? Qb : Kb;
    const int bnn = bn & 1;
#pragma unroll
    for (int mf = 0; mf < 8; mf++) {
      const int lmb = wm*128 + mf*16 + g*4;
#pragma unroll
      for (int nf = 0; nf < 4; nf++) {
        const int ln = wn*64 + nf*16 + c;
#pragma unroll
        for (int r = 0; r < 4; r++) {
          const int lm = lmb + r;
          *(u16*)(sm + lm*512 + ((ln*2) ^ ((lm & 7) << 4))) = f2b(acc[mf][nf][r]);
        }
      }
    }
    __builtin_amdgcn_s_barrier();
#pragma unroll
    for (int it = 0; it < 16; it++) {
      const int gid = it*512 + tid;
      const int lm2 = gid >> 5, gsub = gid & 31;
      bf16x8 v = *(const bf16x8*)(sm + lm2*512 + ((gsub*16) ^ ((lm2 & 7) << 4)));
      const int h = bnn*2 + (gsub >> 4);
      const int d0 = (gsub & 15) * 8;
      *(bf16x8*)(dst0 + ((size_t)(b*4 + h)*1024 + iBase + lm2)*128 + d0) = v;
    }
  } else if (bn < 6) {
#pragma unroll
    for (int mf = 0; mf < 8; mf++) {
      const int lmb = wm*128 + mf*16 + g*4;
#pragma unroll
      for (int nf = 0; nf < 4; nf++) {
        const int ln = wn*64 + nf*16 + c;
        u32 w0, w1;
        asm("v_cvt_pk_bf16_f32 %0, %1, %2" : "=v"(w0) : "v"(acc[mf][nf][0]), "v"(acc[mf][nf][1]));
        asm("v_cvt_pk_bf16_f32 %0, %1, %2" : "=v"(w1) : "v"(acc[mf][nf][2]), "v"(acc[mf][nf][3]));
        uint2 pk; pk.x = w0; pk.y = w1;
        *(uint2*)(sm + ln*512 + ((lmb*2) ^ ((c & 7) << 4))) = pk;
      }
    }
    __builtin_amdgcn_s_barrier();
#pragma unroll
    for (int it = 0; it < 16; it++) {
      const int gid = it*512 + tid;
      const int ln2 = gid >> 5, gsub = gid & 31;
      bf16x8 v = *(const bf16x8*)(sm + ln2*512 + ((gsub*16) ^ ((ln2 & 7) << 4)));
      const int q2 = (bn - 4)*256 + ln2;
      const int h = q2 >> 7, d = q2 & 127;
      *(bf16x8*)(Vt + ((size_t)(b*4 + h)*128 + d)*1024 + iBase + gsub*8) = v;
    }
  } else {
#pragma unroll
    for (int mf = 0; mf < 8; mf++) {
      const int lmb = wm*128 + mf*16 + g*4;
#pragma unroll
      for (int nf = 0; nf < 4; nf++) {
        const int q = (bn - 6)*256 + wn*64 + nf*16 + c;
        if (q < 252) {
          const int h = q / 63, r2 = q - h*63;
#pragma unroll
          for (int r = 0; r < 4; r++)
            RELW[(size_t)((b*4 + h)*1024 + iBase + lmb + r)*64 + r2] = acc[mf][nf][r];
        } else if (q < 504) {
          const int qq = q - 252;
          const int h = qq / 63, r2 = qq - h*63;
#pragma unroll
          for (int r = 0; r < 4; r++)
            RELH[(size_t)((b*4 + h)*1024 + iBase + lmb + r)*64 + r2] = acc[mf][nf][r];
        }
      }
    }
  }
}

// ---------------- attn with KV-split=2: partial O (unnormalized bf16) + (m,l) stats ----------------
// grid (32 bh, 32 = qt | half<<4), 256 threads (4 waves x 16 q). K staged (2-deep), V direct from L2.
__global__ __launch_bounds__(256, 4) void attn_split(
    const u16* __restrict__ Qb, const u16* __restrict__ Kb, const u16* __restrict__ Vt,
    const float* __restrict__ RELW, const float* __restrict__ RELH,
    u16* __restrict__ Opart, float2* __restrict__ ML)
{
  __shared__ char sm[40960];   // K dbuf 2x16KB + Pl 8KB
  char* const Pl = sm + 32768;
  const int tid = threadIdx.x;
  const int w = tid >> 6, l = tid & 63, g = l >> 4, c = l & 15;
  const int bh = blockIdx.x;
  const int qt = blockIdx.y & 15, half = blockIdx.y >> 4;
  const int i0 = qt * 64, jt0 = half * 8;

  bf16x8 qf[4];
  {
    const char* qbase = (const char*)Qb + (size_t)(bh*1024 + i0 + w*16 + c) * 256;
#pragma unroll
    for (int s = 0; s < 4; s++) qf[s] = *(const bf16x8*)(qbase + s*64 + g*16);
  }

  const int i = i0 + w*16 + c;
  const int xi = i & 31, yi = i >> 5;
  const float* rw = RELW + ((size_t)(bh*1024 + i) << 6);
  const float* rhb = RELH + ((size_t)(bh*1024 + i) << 6) + (31 - yi);
  float xwh[2][4];
#pragma unroll
  for (int e = 0; e < 2; e++)
#pragma unroll
    for (int r = 0; r < 4; r++) xwh[e][r] = rw[e*16 + g*4 + r - xi + 31];

  // prologue: yh FIRST (so later waits don't drain K stages), then K tiles jt0, jt0+1
  float yh0 = rhb[jt0*2], yh1 = rhb[jt0*2 + 1];

#define K_STAGE(jt, p)                                                                     \
  {                                                                                        \
    char* Kt_ = sm + (p)*16384;                                                            \
    const int j0b = (jt) * 64;                                                             \
    _Pragma("unroll")                                                                      \
    for (int t = 0; t < 4; t++) {                                                          \
      const int L = (w*4 + t)*1024 + l*16;                                                 \
      const int jr = L >> 8, jb = L & 255;                                                 \
      glds16((const char*)Kb + (size_t)(bh*1024 + j0b + jr) * 256 + (jb ^ ((jr & 7) << 4)),\
             Kt_ + L);                                                                     \
    }                                                                                      \
  }

  K_STAGE(jt0, 0);
  K_STAGE(jt0 + 1, 1);

  f32x4 Oacc[8];
#pragma unroll
  for (int fd = 0; fd < 8; fd++) Oacc[fd] = f32x4{0.f, 0.f, 0.f, 0.f};
  float m_q = -INFINITY, l_q = 0.f;

#pragma unroll
  for (int jj = 0; jj < 8; jj++) {
    const int jt = jt0 + jj;
    const int p = jj & 1;
    if (jj == 0)      { asm volatile("s_waitcnt vmcnt(4)" ::: "memory"); }
    else if (jj == 7) { asm volatile("s_waitcnt vmcnt(2)" ::: "memory"); }
    else              { asm volatile("s_waitcnt vmcnt(6)" ::: "memory"); }
    __builtin_amdgcn_s_barrier();

    const char* Kt_ = sm + p*16384;

    // S' = K Q^T
    f32x4 acc[4];
#pragma unroll
    for (int fn = 0; fn < 4; fn++) acc[fn] = f32x4{0.f, 0.f, 0.f, 0.f};
    __builtin_amdgcn_s_setprio(1);
#pragma unroll
    for (int s = 0; s < 4; s++) {
      const int koff = (s*64 + g*16) ^ ((c & 7) << 4);
#pragma unroll
      for (int fn = 0; fn < 4; fn++) {
        bf16x8 kf = *(const bf16x8*)(Kt_ + (fn*16 + c)*256 + koff);
        acc[fn] = __builtin_amdgcn_mfma_f32_16x16x32_bf16(kf, qf[s], acc[fn], 0, 0, 0);
      }
    }
    __builtin_amdgcn_s_setprio(0);

    // bias: kv = jt*64 + fn*16 + g*4 + r -> xj = (fn&1)*16+g*4+r, yj = jt*2+(fn>>1)
#pragma unroll
    for (int fn = 0; fn < 4; fn++)
#pragma unroll
      for (int r = 0; r < 4; r++)
        acc[fn][r] += xwh[fn & 1][r] + ((fn >> 1) ? yh1 : yh0);

    float mx = fmaxf(fmaxf(fmaxf(acc[0][0], acc[0][1]), fmaxf(acc[0][2], acc[0][3])),
                     fmaxf(fmaxf(acc[1][0], acc[1][1]), fmaxf(acc[1][2], acc[1][3])));
    mx = fmaxf(mx, fmaxf(fmaxf(fmaxf(acc[2][0], acc[2][1]), fmaxf(acc[2][2], acc[2][3])),
                         fmaxf(fmaxf(acc[3][0], acc[3][1]), fmaxf(acc[3][2], acc[3][3]))));
    mx = fmaxf(mx, __shfl_xor(mx, 16));
    mx = fmaxf(mx, __shfl_xor(mx, 32));
    const float mnew = fmaxf(m_q, mx);
    const float scq = __expf(m_q - mnew);
    m_q = mnew;

    float pv[4][4];
    float ps = 0.f;
#pragma unroll
    for (int fn = 0; fn < 4; fn++) {
#pragma unroll
      for (int r = 0; r < 4; r++) {
        pv[fn][r] = __expf(acc[fn][r] - mnew);
        ps += pv[fn][r];
      }
    }
    ps += __shfl_xor(ps, 16);
    ps += __shfl_xor(ps, 32);
    l_q = l_q * scq + ps;

    // next-tile yh prefetch (issued BEFORE the stage so its implicit wait drains only current tile)
    float nyh0 = 0.f, nyh1 = 0.f;
    if (jj < 7) { nyh0 = rhb[(jt + 1)*2]; nyh1 = rhb[(jt + 1)*2 + 1]; }

    // P pack -> Pl[q=c][kv]
    {
      char* pb = Pl + w*2048 + c*128;
      const int swz = (c & 7) << 4;
#pragma unroll
      for (int fn = 0; fn < 4; fn++) {
        u32 w0, w1;
        asm("v_cvt_pk_bf16_f32 %0, %1, %2" : "=v"(w0) : "v"(pv[fn][0]), "v"(pv[fn][1]));
        asm("v_cvt_pk_bf16_f32 %0, %1, %2" : "=v"(w1) : "v"(pv[fn][2]), "v"(pv[fn][3]));
        uint2 pk; pk.x = w0; pk.y = w1;
        *(uint2*)(pb + ((fn*32 + g*8) ^ swz)) = pk;
      }
    }

#pragma unroll
    for (int r = 0; r < 4; r++) {
      const float scr = __shfl(scq, g*4 + r, 16);
#pragma unroll
      for (int fd = 0; fd < 8; fd++) Oacc[fd][r] *= scr;
    }

    // O += P V ; V B-frags direct from global (L2-hot), batches of 4 to bound VGPR
    __builtin_amdgcn_s_setprio(1);
#pragma unroll
    for (int s = 0; s < 2; s++) {
      const int koff = (s*64 + g*16) ^ ((c & 7) << 4);
      bf16x8 pf = *(const bf16x8*)(Pl + w*2048 + c*128 + koff);
      const size_t vbase = (size_t)(bh*128 + c)*1024 + jt*64 + s*32 + g*8;
#pragma unroll
      for (int fb = 0; fb < 2; fb++) {
        bf16x8 vfa[4];
#pragma unroll
        for (int q4 = 0; q4 < 4; q4++)
          vfa[q4] = *(const bf16x8*)(Vt + vbase + (size_t)(fb*4 + q4)*16*1024);
#pragma unroll
        for (int q4 = 0; q4 < 4; q4++)
          Oacc[fb*4 + q4] = __builtin_amdgcn_mfma_f32_16x16x32_bf16(pf, vfa[q4], Oacc[fb*4 + q4], 0, 0, 0);
      }
    }
    __builtin_amdgcn_s_setprio(0);

    __builtin_amdgcn_s_barrier();
    if (jj < 6) K_STAGE(jt + 2, p);
    yh0 = nyh0; yh1 = nyh1;
  }
#undef K_STAGE

  // store unnormalized partial O + stats
  const size_t rbase = (size_t)(half*32 + bh)*1024;
#pragma unroll
  for (int fd = 0; fd < 8; fd++) {
#pragma unroll
    for (int r = 0; r < 4; r++) {
      const int io = i0 + w*16 + g*4 + r;
      Opart[(rbase + io)*128 + fd*16 + c] = f2b(Oacc[fd][r]);
    }
  }
  if (l < 16) {
    float2 s2; s2.x = m_q; s2.y = l_q;
    ML[rbase + i0 + w*16 + l] = s2;
  }
}

// ---------------- merge two KV-split partials; writes IN PLACE over partial 0 ----------------
// grid (32 bh, 32 qblk), 256 threads = 32 rows x 8 d-groups of 16
__global__ __launch_bounds__(256) void attn_merge(
    u16* __restrict__ Opart, const float2* __restrict__ ML)
{
  const int bh = blockIdx.x, qb = blockIdx.y;
  const int t = threadIdx.x;
  const int row = t >> 3, dg = t & 7;
  const int i = qb*32 + row;
  const size_t r0 = (size_t)bh*1024 + i;
  const size_t r1 = (size_t)(32 + bh)*1024 + i;
  const float2 ml0 = ML[r0], ml1 = ML[r1];
  const float m = fmaxf(ml0.x, ml1.x);
  const float w0 = __expf(ml0.x - m), w1 = __expf(ml1.x - m);
  const float linv = 1.0f / (ml0.y*w0 + ml1.y*w1);
  u16* p0 = Opart + r0*128 + dg*16;
  const u16* p1 = Opart + r1*128 + dg*16;
#pragma unroll
  for (int hlf = 0; hlf < 2; hlf++) {
    bf16x8 a = *(const bf16x8*)(p0 + hlf*8);
    bf16x8 b = *(const bf16x8*)(p1 + hlf*8);
    u16 outv[8];
#pragma unroll
    for (int e = 0; e < 8; e++) {
      float va = b2f(((const u16*)&a)[e]);
      float vb = b2f(((const u16*)&b)[e]);
      outv[e] = f2b((va*w0 + vb*w1) * linv);
    }
    *(bf16x8*)(p0 + hlf*8) = *(const bf16x8*)outv;
  }
}

// ---------------- output GEMM (128x128 tile, 4 waves, 2-deep pipeline; A = merged Opart0) ----------
// A layout head-major: row (b*4+h)*1024+i, 128 d-cols; logical A[m=b*1024+i][n=h*128+d].
__global__ __launch_bounds__(256) void gemm_out(
    const u16* __restrict__ A, const u16* __restrict__ Bt, float* __restrict__ outF)
{
  __shared__ char sm[65536];
  const int tid = threadIdx.x;
  const int w = tid >> 6, l = tid & 63, g = l >> 4, c = l & 15;
  const int bm = blockIdx.x, bn = blockIdx.y;
  const int wm = (w >> 1) * 64, wn = (w & 1) * 64;

  f32x4 acc[4][4];
#pragma unroll
  for (int i = 0; i < 4; i++)
#pragma unroll
    for (int j = 0; j < 4; j++) acc[i][j] = f32x4{0.f, 0.f, 0.f, 0.f};

  const char* Ab = (const char*)A;
  const char* Bb = (const char*)Bt;
  const int rsub = l >> 3;
  const int csw = (((l & 7) ^ rsub) << 4);
  const int b_ = bm >> 3;         // batch
  const int iT = (bm & 7) * 128;  // i-base of this tile

#define G_STAGE(kb, p)                                                                    \
  {                                                                                       \
    char* As_ = sm + (p)*32768;                                                           \
    char* Bs_ = As_ + 16384;                                                              \
    const int h_ = (kb) >> 1;                                                             \
    const int dof = ((kb) & 1) * 128;                                                     \
    _Pragma("unroll")                                                                     \
    for (int t = 0; t < 4; t++) {                                                         \
      const int row = (w*4 + t)*8 + rsub;                                                 \
      glds16(Ab + (size_t)((b_*4 + h_)*1024 + iT + row) * 256 + dof + csw,                \
             As_ + (w*4 + t)*1024);                                                       \
      glds16(Bb + (size_t)(bn*128 + row) * 1024 + (kb)*128 + csw, Bs_ + (w*4 + t)*1024);  \
    }                                                                                     \
  }

  G_STAGE(0, 0);
  G_STAGE(1, 1);

#pragma unroll
  for (int kb = 0; kb < 8; kb++) {
    const int p = kb & 1;
    if (kb < 7) { asm volatile("s_waitcnt vmcnt(8)" ::: "memory"); }
    else        { asm volatile("s_waitcnt vmcnt(0)" ::: "memory"); }
    __builtin_amdgcn_s_barrier();
    const char* As_ = sm + p*32768;
    const char* Bs_ = As_ + 16384;
#pragma unroll
    for (int ks = 0; ks < 2; ks++) {
      const int koff = (ks*64 + g*16) ^ ((c & 7) << 4);
      bf16x8 af[4], bfr[4];
#pragma unroll
      for (int mf = 0; mf < 4; mf++)
        af[mf] = *(const bf16x8*)(As_ + (wm + mf*16 + c)*128 + koff);
#pragma unroll
      for (int nf = 0; nf < 4; nf++)
        bfr[nf] = *(const bf16x8*)(Bs_ + (wn + nf*16 + c)*128 + koff);
#pragma unroll
      for (int mf = 0; mf < 4; mf++)
#pragma unroll
        for (int nf = 0; nf < 4; nf++)
          acc[mf][nf] = __builtin_amdgcn_mfma_f32_16x16x32_bf16(af[mf], bfr[nf], acc[mf][nf], 0, 0, 0);
    }
    __builtin_amdgcn_s_barrier();
    if (kb < 6) G_STAGE(kb + 2, p);
  }
#undef G_STAGE

#pragma unroll
  for (int mf = 0; mf < 4; mf++) {
#pragma unroll
    for (int nf = 0; nf < 4; nf++) {
      const int n = bn*128 + wn + nf*16 + c;
#pragma unroll
      for (int r = 0; r < 4; r++) {
        const int m = bm*128 + wm + mf*16 + g*4 + r;
        outF[(size_t)m*512 + n] = acc[mf][nf][r];
      }
    }
  }
}

// ---------------- launcher ----------------
extern "C" void kernel_launch(void* const* d_in, const int* in_sizes, int n_in,
                              void* d_out, int out_size, void* d_ws, size_t ws_size,
                              hipStream_t stream) {
  const float* x   = (const float*)d_in[0];
  const float* Wq  = (const float*)d_in[1];
  const float* Wk  = (const float*)d_in[2];
  const float* Wv  = (const float*)d_in[3];
  const float* Wo  = (const float*)d_in[4];
  const float* pew = (const float*)d_in[5];
  const float* peh = (const float*)d_in[6];

  char* ws = (char*)d_ws;
  u16* xb    = (u16*)ws;    ws += (size_t)8192*512*2;      // 8.39 MB
  u16* WbigT = (u16*)ws;    ws += (size_t)2048*512*2;      // 2.10 MB
  u16* WoT   = (u16*)ws;    ws += (size_t)512*512*2;       // 0.52 MB
  u16* Qb    = (u16*)ws;    ws += (size_t)32*1024*128*2;   // 8.39 MB
  u16* Kb    = (u16*)ws;    ws += (size_t)32*1024*128*2;   // 8.39 MB
  u16* Vt    = (u16*)ws;    ws += (size_t)32*1024*128*2;   // 8.39 MB
  float* RELW = (float*)ws; ws += (size_t)32*1024*64*4;    // 8.39 MB
  float* RELH = (float*)ws; ws += (size_t)32*1024*64*4;    // 8.39 MB
  u16* Opart = (u16*)ws;    ws += (size_t)2*32*1024*128*2; // 16.78 MB (half0 doubles as merged A)
  float2* MLb = (float2*)ws; ws += (size_t)2*32*1024*8;    // 0.52 MB   (total ~70.3 MB)

  castx<<<4096, 256, 0, stream>>>(x, xb);
  buildw<<<2056, 256, 0, stream>>>(Wq, Wk, Wv, Wo, WbigT, WoT);
  wpe_kernel<<<512, 256, 0, stream>>>(Wq, pew, peh, WbigT);
  gemm256<<<dim3(32, 8), 512, 0, stream>>>(xb, WbigT, Qb, Kb, Vt, RELW, RELH);
  attn_split<<<dim3(32, 32), 256, 0, stream>>>(Qb, Kb, Vt, RELW, RELH, Opart, MLb);
  attn_merge<<<dim3(32, 32), 256, 0, stream>>>(Opart, MLb);
  gemm_out<<<dim3(64, 4), 256, 0, stream>>>(Opart, WoT, (float*)d_out);
}

// Round 9
// 106.223 us; speedup vs baseline: 1.3835x; 1.3835x over previous
//
#include <hip/hip_runtime.h>
#include <math.h>

typedef unsigned short u16;
typedef unsigned int u32;
typedef __bf16 bf16x8 __attribute__((ext_vector_type(8)));
typedef float f32x4 __attribute__((ext_vector_type(4)));

__device__ __forceinline__ u16 f2b(float f) {
  u32 u = __builtin_bit_cast(u32, f);
  u32 r = (u + 0x7FFFu + ((u >> 16) & 1u)) >> 16;
  return (u16)r;
}

__device__ __forceinline__ float b2f(u16 b) {
  u32 u = ((u32)b) << 16;
  return __builtin_bit_cast(float, u);
}

__device__ __forceinline__ void glds16(const void* g, void* lds) {
  __builtin_amdgcn_global_load_lds(
      (const __attribute__((address_space(1))) void*)(void*)(const_cast<void*>(g)),
      (__attribute__((address_space(3))) void*)lds, 16, 0, 0);
}

// ---------------- prep kernels ----------------

__global__ __launch_bounds__(256) void castx(const float* __restrict__ x, u16* __restrict__ xb) {
  int idx = blockIdx.x * 256 + threadIdx.x;
  float4 v = ((const float4*)x)[idx];
  ushort4 o;
  o.x = f2b(v.x); o.y = f2b(v.y); o.z = f2b(v.z); o.w = f2b(v.w);
  ((ushort4*)xb)[idx] = o;
}

__global__ __launch_bounds__(256) void buildw(const float* __restrict__ Wq, const float* __restrict__ Wk,
                                              const float* __restrict__ Wv, const float* __restrict__ Wo,
                                              u16* __restrict__ WbigT, u16* __restrict__ WoT) {
  const float SCALE = 0.08838834764831845f;  // 1/sqrt(128)
  int row = blockIdx.x;  // 0..2055
  int t = threadIdx.x;
  if (row < 512) {
    for (int k = t; k < 512; k += 256) WbigT[row*512 + k] = f2b(Wq[k*512 + row] * SCALE);
  } else if (row < 1024) {
    int n = row - 512;
    for (int k = t; k < 512; k += 256) WbigT[row*512 + k] = f2b(Wk[k*512 + n]);
  } else if (row < 1536) {
    int n = row - 1024;
    for (int k = t; k < 512; k += 256) WbigT[row*512 + k] = f2b(Wv[k*512 + n]);
  } else if (row < 1544) {
    int rr = row - 1536 + 2040;
    for (int k = t; k < 512; k += 256) WbigT[rr*512 + k] = 0;
  } else {
    int n = row - 1544;
    for (int k = t; k < 512; k += 256) WoT[n*512 + k] = f2b(Wo[k*512 + n]);
  }
}

__global__ __launch_bounds__(256) void wpe_kernel(const float* __restrict__ Wq, const float* __restrict__ pew,
                                                  const float* __restrict__ peh, u16* __restrict__ WbigT) {
  int k = blockIdx.x;  // 0..511
  int t = threadIdx.x;
  __shared__ float wrow[512];
  for (int j = t; j < 512; j += 256) wrow[j] = Wq[k*512 + j];
  __syncthreads();
  if (t < 252) {
    int h = t / 63, r = t - h*63;
    float aw = 0.f, ah = 0.f;
    for (int d = 0; d < 128; d++) {
      float qv = wrow[h*128 + d];
      aw += qv * pew[d*63 + r];
      ah += qv * peh[d*63 + r];
    }
    const float SCALE = 0.08838834764831845f;
    WbigT[(size_t)(1536 + t)*512 + k] = f2b(aw * SCALE);
    WbigT[(size_t)(1788 + t)*512 + k] = f2b(ah * SCALE);
  }
}

// ---------------- fused QKV+REL GEMM: 256x256 tile, 8 waves (2Mx4N), BK=64 (R5, proven) --------
__global__ __launch_bounds__(512) void gemm256(
    const u16* __restrict__ A, const u16* __restrict__ Bt,
    u16* __restrict__ Qb, u16* __restrict__ Kb, u16* __restrict__ Vt,
    float* __restrict__ RELW, float* __restrict__ RELH)
{
  __shared__ char sm[131072];
  const int tid = threadIdx.x;
  const int w = tid >> 6, l = tid & 63, g = l >> 4, c = l & 15;
  const int bm = blockIdx.x, bn = blockIdx.y;
  const int wm = w >> 2, wn = w & 3;

  f32x4 acc[8][4];
#pragma unroll
  for (int i = 0; i < 8; i++)
#pragma unroll
    for (int j = 0; j < 4; j++) acc[i][j] = f32x4{0.f, 0.f, 0.f, 0.f};

  const char* Ab = (const char*)A;
  const char* Bb = (const char*)Bt;
  const int rsub = l >> 3;
  const int csw = (((l & 7) ^ rsub) << 4);

#define G_STAGE(kb, p)                                                                    \
  {                                                                                       \
    char* As_ = sm + (p)*65536;                                                           \
    char* Bs_ = As_ + 32768;                                                              \
    const int kbyte = (kb) * 128;                                                         \
    _Pragma("unroll")                                                                     \
    for (int i2 = 0; i2 < 4; i2++) {                                                      \
      const int row = i2*64 + w*8 + rsub;                                                 \
      glds16(Ab + (size_t)(bm*256 + row) * 1024 + kbyte + csw, As_ + i2*8192 + w*1024);   \
      glds16(Bb + (size_t)(bn*256 + row) * 1024 + kbyte + csw, Bs_ + i2*8192 + w*1024);   \
    }                                                                                     \
  }

  G_STAGE(0, 0);
  G_STAGE(1, 1);

#pragma unroll
  for (int kb = 0; kb < 8; kb++) {
    const int p = kb & 1;
    if (kb < 7) { asm volatile("s_waitcnt vmcnt(8)" ::: "memory"); }
    else        { asm volatile("s_waitcnt vmcnt(0)" ::: "memory"); }
    __builtin_amdgcn_s_barrier();
    const char* As_ = sm + p*65536;
    const char* Bs_ = As_ + 32768;
#pragma unroll
    for (int ks = 0; ks < 2; ks++) {
      const int koff = (ks*64 + g*16) ^ ((c & 7) << 4);
      bf16x8 af[8], bfr[4];
#pragma unroll
      for (int mf = 0; mf < 8; mf++)
        af[mf] = *(const bf16x8*)(As_ + (wm*128 + mf*16 + c)*128 + koff);
#pragma unroll
      for (int nf = 0; nf < 4; nf++)
        bfr[nf] = *(const bf16x8*)(Bs_ + (wn*64 + nf*16 + c)*128 + koff);
#pragma unroll
      for (int mf = 0; mf < 8; mf++)
#pragma unroll
        for (int nf = 0; nf < 4; nf++)
          acc[mf][nf] = __builtin_amdgcn_mfma_f32_16x16x32_bf16(af[mf], bfr[nf], acc[mf][nf], 0, 0, 0);
    }
    __builtin_amdgcn_s_barrier();
    if (kb < 6) G_STAGE(kb + 2, p);
  }
#undef G_STAGE

  const int b = bm >> 2;
  const int iBase = (bm & 3) * 256;

  if (bn < 4) {
    u16* dst0 = (bn < 2) ? Qb : Kb;
    const int bnn = bn & 1;
#pragma unroll
    for (int mf = 0; mf < 8; mf++) {
      const int lmb = wm*128 + mf*16 + g*4;
#pragma unroll
      for (int nf = 0; nf < 4; nf++) {
        const int ln = wn*64 + nf*16 + c;
#pragma unroll
        for (int r = 0; r < 4; r++) {
          const int lm = lmb + r;
          *(u16*)(sm + lm*512 + ((ln*2) ^ ((lm & 7) << 4))) = f2b(acc[mf][nf][r]);
        }
      }
    }
    __builtin_amdgcn_s_barrier();
#pragma unroll
    for (int it = 0; it < 16; it++) {
      const int gid = it*512 + tid;
      const int lm2 = gid >> 5, gsub = gid & 31;
      bf16x8 v = *(const bf16x8*)(sm + lm2*512 + ((gsub*16) ^ ((lm2 & 7) << 4)));
      const int h = bnn*2 + (gsub >> 4);
      const int d0 = (gsub & 15) * 8;
      *(bf16x8*)(dst0 + ((size_t)(b*4 + h)*1024 + iBase + lm2)*128 + d0) = v;
    }
  } else if (bn < 6) {
#pragma unroll
    for (int mf = 0; mf < 8; mf++) {
      const int lmb = wm*128 + mf*16 + g*4;
#pragma unroll
      for (int nf = 0; nf < 4; nf++) {
        const int ln = wn*64 + nf*16 + c;
        u32 w0, w1;
        asm("v_cvt_pk_bf16_f32 %0, %1, %2" : "=v"(w0) : "v"(acc[mf][nf][0]), "v"(acc[mf][nf][1]));
        asm("v_cvt_pk_bf16_f32 %0, %1, %2" : "=v"(w1) : "v"(acc[mf][nf][2]), "v"(acc[mf][nf][3]));
        uint2 pk; pk.x = w0; pk.y = w1;
        *(uint2*)(sm + ln*512 + ((lmb*2) ^ ((c & 7) << 4))) = pk;
      }
    }
    __builtin_amdgcn_s_barrier();
#pragma unroll
    for (int it = 0; it < 16; it++) {
      const int gid = it*512 + tid;
      const int ln2 = gid >> 5, gsub = gid & 31;
      bf16x8 v = *(const bf16x8*)(sm + ln2*512 + ((gsub*16) ^ ((ln2 & 7) << 4)));
      const int q2 = (bn - 4)*256 + ln2;
      const int h = q2 >> 7, d = q2 & 127;
      *(bf16x8*)(Vt + ((size_t)(b*4 + h)*128 + d)*1024 + iBase + gsub*8) = v;
    }
  } else {
#pragma unroll
    for (int mf = 0; mf < 8; mf++) {
      const int lmb = wm*128 + mf*16 + g*4;
#pragma unroll
      for (int nf = 0; nf < 4; nf++) {
        const int q = (bn - 6)*256 + wn*64 + nf*16 + c;
        if (q < 252) {
          const int h = q / 63, r2 = q - h*63;
#pragma unroll
          for (int r = 0; r < 4; r++)
            RELW[(size_t)((b*4 + h)*1024 + iBase + lmb + r)*64 + r2] = acc[mf][nf][r];
        } else if (q < 504) {
          const int qq = q - 252;
          const int h = qq / 63, r2 = qq - h*63;
#pragma unroll
          for (int r = 0; r < 4; r++)
            RELH[(size_t)((b*4 + h)*1024 + iBase + lmb + r)*64 + r2] = acc[mf][nf][r];
        }
      }
    }
  }
}

// ---------------- attn, KV-split=2, KVBLK=64 single-buffered (40KB LDS -> 4 blocks/CU) --------
// grid (32 bh, 32 = qt | half<<4), 256 threads (4 waves x 16 q). Compute code = R4 (proven).
__global__ __launch_bounds__(256) void attn_split(
    const u16* __restrict__ Qb, const u16* __restrict__ Kb, const u16* __restrict__ Vt,
    const float* __restrict__ RELW, const float* __restrict__ RELH,
    u16* __restrict__ Opart, float2* __restrict__ ML)
{
  __shared__ char sm[40960];   // Kt 16KB @0, Vts 16KB @16384, Pl 8KB @32768
  char* const Pl = sm + 32768;
  const int tid = threadIdx.x;
  const int w = tid >> 6, l = tid & 63, g = l >> 4, c = l & 15;
  const int bh = blockIdx.x;
  const int qt = blockIdx.y & 15, half = blockIdx.y >> 4;
  const int i0 = qt * 64, jt0 = half * 8;

  bf16x8 qf[4];
  {
    const char* qbase = (const char*)Qb + (size_t)(bh*1024 + i0 + w*16 + c) * 256;
#pragma unroll
    for (int s = 0; s < 4; s++) qf[s] = *(const bf16x8*)(qbase + s*64 + g*16);
  }

  const int i = i0 + w*16 + c;
  const int xi = i & 31, yi = i >> 5;
  const float* rw = RELW + ((size_t)(bh*1024 + i) << 6);
  const float* rhb = RELH + ((size_t)(bh*1024 + i) << 6) + (31 - yi);
  float xwh[2][4];
#pragma unroll
  for (int e = 0; e < 2; e++)
#pragma unroll
    for (int r = 0; r < 4; r++) xwh[e][r] = rw[e*16 + g*4 + r - xi + 31];

  f32x4 Oacc[8];
#pragma unroll
  for (int fd = 0; fd < 8; fd++) Oacc[fd] = f32x4{0.f, 0.f, 0.f, 0.f};
  float m_q = -INFINITY, l_q = 0.f;

  // single-buffer stage of one 64-kv tile; dest strictly base + lane*16 (rule 21),
  // all permutation on the SOURCE address (proven R4 pattern).
#define KV_STAGE(jt)                                                                       \
  {                                                                                        \
    char* Kt_ = sm;                                                                        \
    char* Vs_ = sm + 16384;                                                                \
    const int j0b = (jt) * 64;                                                             \
    _Pragma("unroll")                                                                      \
    for (int t = 0; t < 4; t++) {                                                          \
      const int L = (w*4 + t)*1024 + l*16;                                                 \
      const int jr = L >> 8, jb = L & 255;                                                 \
      glds16((const char*)Kb + (size_t)(bh*1024 + j0b + jr) * 256 + (jb ^ ((jr & 7) << 4)),\
             Kt_ + L);                                                                     \
      const int dr = L >> 7, db = L & 127;                                                 \
      glds16((const char*)Vt + (size_t)(bh*128 + dr) * 2048 + j0b*2 + (db ^ ((dr & 7) << 4)),\
             Vs_ + L);                                                                     \
    }                                                                                      \
  }

  for (int jj = 0; jj < 8; jj++) {
    const int jt = jt0 + jj;
    const float yh0 = rhb[jt*2], yh1 = rhb[jt*2 + 1];
    KV_STAGE(jt);
    asm volatile("s_waitcnt vmcnt(0)" ::: "memory");
    __builtin_amdgcn_s_barrier();

    const char* Kt_ = sm;
    const char* Vs_ = sm + 16384;

    // S' = K Q^T
    f32x4 acc[4];
#pragma unroll
    for (int fn = 0; fn < 4; fn++) acc[fn] = f32x4{0.f, 0.f, 0.f, 0.f};
    __builtin_amdgcn_s_setprio(1);
#pragma unroll
    for (int s = 0; s < 4; s++) {
      const int koff = (s*64 + g*16) ^ ((c & 7) << 4);
#pragma unroll
      for (int fn = 0; fn < 4; fn++) {
        bf16x8 kf = *(const bf16x8*)(Kt_ + (fn*16 + c)*256 + koff);
        acc[fn] = __builtin_amdgcn_mfma_f32_16x16x32_bf16(kf, qf[s], acc[fn], 0, 0, 0);
      }
    }
    __builtin_amdgcn_s_setprio(0);

    // bias: kv = jt*64 + fn*16 + g*4 + r -> xj = (fn&1)*16+g*4+r, yj = jt*2+(fn>>1)
#pragma unroll
    for (int fn = 0; fn < 4; fn++)
#pragma unroll
      for (int r = 0; r < 4; r++)
        acc[fn][r] += xwh[fn & 1][r] + ((fn >> 1) ? yh1 : yh0);

    float mx = fmaxf(fmaxf(fmaxf(acc[0][0], acc[0][1]), fmaxf(acc[0][2], acc[0][3])),
                     fmaxf(fmaxf(acc[1][0], acc[1][1]), fmaxf(acc[1][2], acc[1][3])));
    mx = fmaxf(mx, fmaxf(fmaxf(fmaxf(acc[2][0], acc[2][1]), fmaxf(acc[2][2], acc[2][3])),
                         fmaxf(fmaxf(acc[3][0], acc[3][1]), fmaxf(acc[3][2], acc[3][3]))));
    mx = fmaxf(mx, __shfl_xor(mx, 16));
    mx = fmaxf(mx, __shfl_xor(mx, 32));
    const float mnew = fmaxf(m_q, mx);
    const float scq = __expf(m_q - mnew);
    m_q = mnew;

    float pv[4][4];
    float ps = 0.f;
#pragma unroll
    for (int fn = 0; fn < 4; fn++) {
#pragma unroll
      for (int r = 0; r < 4; r++) {
        pv[fn][r] = __expf(acc[fn][r] - mnew);
        ps += pv[fn][r];
      }
    }
    ps += __shfl_xor(ps, 16);
    ps += __shfl_xor(ps, 32);
    l_q = l_q * scq + ps;

    // P pack -> Pl[q=c][kv]
    {
      char* pb = Pl + w*2048 + c*128;
      const int swz = (c & 7) << 4;
#pragma unroll
      for (int fn = 0; fn < 4; fn++) {
        u32 w0, w1;
        asm("v_cvt_pk_bf16_f32 %0, %1, %2" : "=v"(w0) : "v"(pv[fn][0]), "v"(pv[fn][1]));
        asm("v_cvt_pk_bf16_f32 %0, %1, %2" : "=v"(w1) : "v"(pv[fn][2]), "v"(pv[fn][3]));
        uint2 pk; pk.x = w0; pk.y = w1;
        *(uint2*)(pb + ((fn*32 + g*8) ^ swz)) = pk;
      }
    }

#pragma unroll
    for (int r = 0; r < 4; r++) {
      const float scr = __shfl(scq, g*4 + r, 16);
#pragma unroll
      for (int fd = 0; fd < 8; fd++) Oacc[fd][r] *= scr;
    }

    // O += P V
    __builtin_amdgcn_s_setprio(1);
#pragma unroll
    for (int s = 0; s < 2; s++) {
      const int koff = (s*64 + g*16) ^ ((c & 7) << 4);
      bf16x8 pf = *(const bf16x8*)(Pl + w*2048 + c*128 + koff);
#pragma unroll
      for (int fd = 0; fd < 8; fd++) {
        bf16x8 vf = *(const bf16x8*)(Vs_ + (fd*16 + c)*128 + koff);
        Oacc[fd] = __builtin_amdgcn_mfma_f32_16x16x32_bf16(pf, vf, Oacc[fd], 0, 0, 0);
      }
    }
    __builtin_amdgcn_s_setprio(0);

    __builtin_amdgcn_s_barrier();   // all waves done reading before next stage overwrites
  }
#undef KV_STAGE

  // store unnormalized partial O + (m,l)
  const size_t rbase = (size_t)(half*32 + bh)*1024;
#pragma unroll
  for (int fd = 0; fd < 8; fd++) {
#pragma unroll
    for (int r = 0; r < 4; r++) {
      const int io = i0 + w*16 + g*4 + r;
      Opart[(rbase + io)*128 + fd*16 + c] = f2b(Oacc[fd][r]);
    }
  }
  if (l < 16) {
    float2 s2; s2.x = m_q; s2.y = l_q;
    ML[rbase + i0 + w*16 + l] = s2;
  }
}

// ---------------- merge two KV-split partials; writes IN PLACE over partial 0 (R7, proven) ----
__global__ __launch_bounds__(256) void attn_merge(
    u16* __restrict__ Opart, const float2* __restrict__ ML)
{
  const int bh = blockIdx.x, qb = blockIdx.y;
  const int t = threadIdx.x;
  const int row = t >> 3, dg = t & 7;
  const int i = qb*32 + row;
  const size_t r0 = (size_t)bh*1024 + i;
  const size_t r1 = (size_t)(32 + bh)*1024 + i;
  const float2 ml0 = ML[r0], ml1 = ML[r1];
  const float m = fmaxf(ml0.x, ml1.x);
  const float w0 = __expf(ml0.x - m), w1 = __expf(ml1.x - m);
  const float linv = 1.0f / (ml0.y*w0 + ml1.y*w1);
  u16* p0 = Opart + r0*128 + dg*16;
  const u16* p1 = Opart + r1*128 + dg*16;
#pragma unroll
  for (int hlf = 0; hlf < 2; hlf++) {
    bf16x8 a = *(const bf16x8*)(p0 + hlf*8);
    bf16x8 b = *(const bf16x8*)(p1 + hlf*8);
    u16 outv[8];
#pragma unroll
    for (int e = 0; e < 8; e++) {
      float va = b2f(((const u16*)&a)[e]);
      float vb = b2f(((const u16*)&b)[e]);
      outv[e] = f2b((va*w0 + vb*w1) * linv);
    }
    *(bf16x8*)(p0 + hlf*8) = *(const bf16x8*)outv;
  }
}

// ---------------- output GEMM (128x128 tile, 2-deep pipeline; A = merged Opart0, head-major) --
__global__ __launch_bounds__(256) void gemm_out(
    const u16* __restrict__ A, const u16* __restrict__ Bt, float* __restrict__ outF)
{
  __shared__ char sm[65536];
  const int tid = threadIdx.x;
  const int w = tid >> 6, l = tid & 63, g = l >> 4, c = l & 15;
  const int bm = blockIdx.x, bn = blockIdx.y;
  const int wm = (w >> 1) * 64, wn = (w & 1) * 64;

  f32x4 acc[4][4];
#pragma unroll
  for (int i = 0; i < 4; i++)
#pragma unroll
    for (int j = 0; j < 4; j++) acc[i][j] = f32x4{0.f, 0.f, 0.f, 0.f};

  const char* Ab = (const char*)A;
  const char* Bb = (const char*)Bt;
  const int rsub = l >> 3;
  const int csw = (((l & 7) ^ rsub) << 4);
  const int b_ = bm >> 3;
  const int iT = (bm & 7) * 128;

#define G_STAGE(kb, p)                                                                    \
  {                                                                                       \
    char* As_ = sm + (p)*32768;                                                           \
    char* Bs_ = As_ + 16384;                                                              \
    const int h_ = (kb) >> 1;                                                             \
    const int dof = ((kb) & 1) * 128;                                                     \
    _Pragma("unroll")                                                                     \
    for (int t = 0; t < 4; t++) {                                                         \
      const int row = (w*4 + t)*8 + rsub;                                                 \
      glds16(Ab + (size_t)((b_*4 + h_)*1024 + iT + row) * 256 + dof + csw,                \
             As_ + (w*4 + t)*1024);                                                       \
      glds16(Bb + (size_t)(bn*128 + row) * 1024 + (kb)*128 + csw, Bs_ + (w*4 + t)*1024);  \
    }                                                                                     \
  }

  G_STAGE(0, 0);
  G_STAGE(1, 1);

#pragma unroll
  for (int kb = 0; kb < 8; kb++) {
    const int p = kb & 1;
    if (kb < 7) { asm volatile("s_waitcnt vmcnt(8)" ::: "memory"); }
    else        { asm volatile("s_waitcnt vmcnt(0)" ::: "memory"); }
    __builtin_amdgcn_s_barrier();
    const char* As_ = sm + p*32768;
    const char* Bs_ = As_ + 16384;
#pragma unroll
    for (int ks = 0; ks < 2; ks++) {
      const int koff = (ks*64 + g*16) ^ ((c & 7) << 4);
      bf16x8 af[4], bfr[4];
#pragma unroll
      for (int mf = 0; mf < 4; mf++)
        af[mf] = *(const bf16x8*)(As_ + (wm + mf*16 + c)*128 + koff);
#pragma unroll
      for (int nf = 0; nf < 4; nf++)
        bfr[nf] = *(const bf16x8*)(Bs_ + (wn + nf*16 + c)*128 + koff);
#pragma unroll
      for (int mf = 0; mf < 4; mf++)
#pragma unroll
        for (int nf = 0; nf < 4; nf++)
          acc[mf][nf] = __builtin_amdgcn_mfma_f32_16x16x32_bf16(af[mf], bfr[nf], acc[mf][nf], 0, 0, 0);
    }
    __builtin_amdgcn_s_barrier();
    if (kb < 6) G_STAGE(kb + 2, p);
  }
#undef G_STAGE

#pragma unroll
  for (int mf = 0; mf < 4; mf++) {
#pragma unroll
    for (int nf = 0; nf < 4; nf++) {
      const int n = bn*128 + wn + nf*16 + c;
#pragma unroll
      for (int r = 0; r < 4; r++) {
        const int m = bm*128 + wm + mf*16 + g*4 + r;
        outF[(size_t)m*512 + n] = acc[mf][nf][r];
      }
    }
  }
}

// ---------------- launcher ----------------
extern "C" void kernel_launch(void* const* d_in, const int* in_sizes, int n_in,
                              void* d_out, int out_size, void* d_ws, size_t ws_size,
                              hipStream_t stream) {
  const float* x   = (const float*)d_in[0];
  const float* Wq  = (const float*)d_in[1];
  const float* Wk  = (const float*)d_in[2];
  const float* Wv  = (const float*)d_in[3];
  const float* Wo  = (const float*)d_in[4];
  const float* pew = (const float*)d_in[5];
  const float* peh = (const float*)d_in[6];

  char* ws = (char*)d_ws;
  u16* xb    = (u16*)ws;    ws += (size_t)8192*512*2;
  u16* WbigT = (u16*)ws;    ws += (size_t)2048*512*2;
  u16* WoT   = (u16*)ws;    ws += (size_t)512*512*2;
  u16* Qb    = (u16*)ws;    ws += (size_t)32*1024*128*2;
  u16* Kb    = (u16*)ws;    ws += (size_t)32*1024*128*2;
  u16* Vt    = (u16*)ws;    ws += (size_t)32*1024*128*2;
  float* RELW = (float*)ws; ws += (size_t)32*1024*64*4;
  float* RELH = (float*)ws; ws += (size_t)32*1024*64*4;
  u16* Opart = (u16*)ws;    ws += (size_t)2*32*1024*128*2;
  float2* MLb = (float2*)ws; ws += (size_t)2*32*1024*8;

  castx<<<4096, 256, 0, stream>>>(x, xb);
  buildw<<<2056, 256, 0, stream>>>(Wq, Wk, Wv, Wo, WbigT, WoT);
  wpe_kernel<<<512, 256, 0, stream>>>(Wq, pew, peh, WbigT);
  gemm256<<<dim3(32, 8), 512, 0, stream>>>(xb, WbigT, Qb, Kb, Vt, RELW, RELH);
  attn_split<<<dim3(32, 32), 256, 0, stream>>>(Qb, Kb, Vt, RELW, RELH, Opart, MLb);
  attn_merge<<<dim3(32, 32), 256, 0, stream>>>(Opart, MLb);
  gemm_out<<<dim3(64, 4), 256, 0, stream>>>(Opart, WoT, (float*)d_out);
}

// Round 10
// 97.323 us; speedup vs baseline: 1.5100x; 1.0914x over previous
//
#include <hip/hip_runtime.h>
#include <math.h>

typedef unsigned short u16;
typedef unsigned int u32;
typedef __bf16 bf16x8 __attribute__((ext_vector_type(8)));
typedef float f32x4 __attribute__((ext_vector_type(4)));

__device__ __forceinline__ u16 f2b(float f) {
  u32 u = __builtin_bit_cast(u32, f);
  u32 r = (u + 0x7FFFu + ((u >> 16) & 1u)) >> 16;
  return (u16)r;
}

__device__ __forceinline__ void glds16(const void* g, void* lds) {
  __builtin_amdgcn_global_load_lds(
      (const __attribute__((address_space(1))) void*)(void*)(const_cast<void*>(g)),
      (__attribute__((address_space(3))) void*)lds, 16, 0, 0);
}

// ---------------- prep kernels ----------------

__global__ __launch_bounds__(256) void castx(const float* __restrict__ x, u16* __restrict__ xb) {
  int idx = blockIdx.x * 256 + threadIdx.x;
  float4 v = ((const float4*)x)[idx];
  ushort4 o;
  o.x = f2b(v.x); o.y = f2b(v.y); o.z = f2b(v.z); o.w = f2b(v.w);
  ((ushort4*)xb)[idx] = o;
}

__global__ __launch_bounds__(256) void buildw(const float* __restrict__ Wq, const float* __restrict__ Wk,
                                              const float* __restrict__ Wv, const float* __restrict__ Wo,
                                              u16* __restrict__ WbigT, u16* __restrict__ WoT) {
  const float SCALE = 0.08838834764831845f;  // 1/sqrt(128)
  int row = blockIdx.x;  // 0..2055
  int t = threadIdx.x;
  if (row < 512) {
    for (int k = t; k < 512; k += 256) WbigT[row*512 + k] = f2b(Wq[k*512 + row] * SCALE);
  } else if (row < 1024) {
    int n = row - 512;
    for (int k = t; k < 512; k += 256) WbigT[row*512 + k] = f2b(Wk[k*512 + n]);
  } else if (row < 1536) {
    int n = row - 1024;
    for (int k = t; k < 512; k += 256) WbigT[row*512 + k] = f2b(Wv[k*512 + n]);
  } else if (row < 1544) {
    int rr = row - 1536 + 2040;
    for (int k = t; k < 512; k += 256) WbigT[rr*512 + k] = 0;
  } else {
    int n = row - 1544;
    for (int k = t; k < 512; k += 256) WoT[n*512 + k] = f2b(Wo[k*512 + n]);
  }
}

__global__ __launch_bounds__(256) void wpe_kernel(const float* __restrict__ Wq, const float* __restrict__ pew,
                                                  const float* __restrict__ peh, u16* __restrict__ WbigT) {
  int k = blockIdx.x;  // 0..511
  int t = threadIdx.x;
  __shared__ float wrow[512];
  for (int j = t; j < 512; j += 256) wrow[j] = Wq[k*512 + j];
  __syncthreads();
  if (t < 252) {
    int h = t / 63, r = t - h*63;
    float aw = 0.f, ah = 0.f;
    for (int d = 0; d < 128; d++) {
      float qv = wrow[h*128 + d];
      aw += qv * pew[d*63 + r];
      ah += qv * peh[d*63 + r];
    }
    const float SCALE = 0.08838834764831845f;
    WbigT[(size_t)(1536 + t)*512 + k] = f2b(aw * SCALE);
    WbigT[(size_t)(1788 + t)*512 + k] = f2b(ah * SCALE);
  }
}

// ---------------- fused QKV+REL GEMM: 256x256 tile, 8 waves (2Mx4N), BK=64 ----------------
// Phase-interleaved schedule (T3+T4+T5): per K-tile two phases; half-tile prefetches
// (A-half / B-half, 4 glds16 each) issued INSIDE compute phases; counted vmcnt at tile
// entry only (8 / 4 / 0), never drained mid-pipeline. Race-safety via barrier ordering:
//   - B(buf p) is only ds_read in phase A -> overwrite legal after phase-A barrier.
//   - A(buf p) read through phase B       -> overwrite legal after tile-end barrier.
__global__ __launch_bounds__(512) void gemm256(
    const u16* __restrict__ A, const u16* __restrict__ Bt,
    u16* __restrict__ Qb, u16* __restrict__ Kb, u16* __restrict__ Vt,
    float* __restrict__ RELW, float* __restrict__ RELH)
{
  __shared__ char sm[131072];   // buf p at p*65536: A 32KB + B 32KB
  const int tid = threadIdx.x;
  const int w = tid >> 6, l = tid & 63, g = l >> 4, c = l & 15;
  const int bm = blockIdx.x, bn = blockIdx.y;
  const int wm = w >> 2, wn = w & 3;   // 2 x 4 waves

  f32x4 acc[8][4];
#pragma unroll
  for (int i = 0; i < 8; i++)
#pragma unroll
    for (int j = 0; j < 4; j++) acc[i][j] = f32x4{0.f, 0.f, 0.f, 0.f};

  const char* Ab = (const char*)A;
  const char* Bb = (const char*)Bt;
  const int rsub = l >> 3;
  const int csw = (((l & 7) ^ rsub) << 4);

#define A_STAGE(kb, p)                                                                    \
  {                                                                                       \
    char* As_ = sm + (p)*65536;                                                           \
    const int kbyte = (kb) * 128;                                                         \
    _Pragma("unroll")                                                                     \
    for (int i2 = 0; i2 < 4; i2++) {                                                      \
      const int row = i2*64 + w*8 + rsub;                                                 \
      glds16(Ab + (size_t)(bm*256 + row) * 1024 + kbyte + csw, As_ + i2*8192 + w*1024);   \
    }                                                                                     \
  }
#define B_STAGE(kb, p)                                                                    \
  {                                                                                       \
    char* Bs_ = sm + (p)*65536 + 32768;                                                   \
    const int kbyte = (kb) * 128;                                                         \
    _Pragma("unroll")                                                                     \
    for (int i2 = 0; i2 < 4; i2++) {                                                      \
      const int row = i2*64 + w*8 + rsub;                                                 \
      glds16(Bb + (size_t)(bn*256 + row) * 1024 + kbyte + csw, Bs_ + i2*8192 + w*1024);   \
    }                                                                                     \
  }

  // prologue: tiles 0,1 fully staged (order: B0 A0 B1 A1 -> 16 ops)
  B_STAGE(0, 0); A_STAGE(0, 0);
  B_STAGE(1, 1); A_STAGE(1, 1);

#pragma unroll
  for (int kb = 0; kb < 8; kb++) {
    const int p = kb & 1;
    // tile entry: wait for tile kb's A+B (outstanding newer: B(kb+1) only in steady state)
    if (kb == 0)      { asm volatile("s_waitcnt vmcnt(8)" ::: "memory"); }
    else if (kb < 7)  { asm volatile("s_waitcnt vmcnt(4)" ::: "memory"); }
    else              { asm volatile("s_waitcnt vmcnt(0)" ::: "memory"); }
    __builtin_amdgcn_s_barrier();

    const char* As_ = sm + p*65536;
    const char* Bs_ = As_ + 32768;

    // ---- phase A: read all bf + af(mf0-3); prefetch A(kb+1) -> buf p^1; MFMA mf0-3
    bf16x8 bf[4][2], af[4][2];
#pragma unroll
    for (int ks = 0; ks < 2; ks++) {
      const int koff = (ks*64 + g*16) ^ ((c & 7) << 4);
#pragma unroll
      for (int mf = 0; mf < 4; mf++)
        af[mf][ks] = *(const bf16x8*)(As_ + (wm*128 + mf*16 + c)*128 + koff);
#pragma unroll
      for (int nf = 0; nf < 4; nf++)
        bf[nf][ks] = *(const bf16x8*)(Bs_ + (wn*64 + nf*16 + c)*128 + koff);
    }
    if (kb >= 1 && kb < 7) A_STAGE(kb + 1, p ^ 1);
    __builtin_amdgcn_s_setprio(1);
#pragma unroll
    for (int ks = 0; ks < 2; ks++)
#pragma unroll
      for (int mf = 0; mf < 4; mf++)
#pragma unroll
        for (int nf = 0; nf < 4; nf++)
          acc[mf][nf] = __builtin_amdgcn_mfma_f32_16x16x32_bf16(af[mf][ks], bf[nf][ks], acc[mf][nf], 0, 0, 0);
    __builtin_amdgcn_s_setprio(0);
    __builtin_amdgcn_s_barrier();   // all waves' B-reads retired -> B(buf p) free

    // ---- phase B: read af(mf4-7); prefetch B(kb+2) -> buf p; MFMA mf4-7 (bf in regs)
#pragma unroll
    for (int ks = 0; ks < 2; ks++) {
      const int koff = (ks*64 + g*16) ^ ((c & 7) << 4);
#pragma unroll
      for (int mf = 0; mf < 4; mf++)
        af[mf][ks] = *(const bf16x8*)(As_ + (wm*128 + (mf + 4)*16 + c)*128 + koff);
    }
    if (kb < 6) B_STAGE(kb + 2, p);
    __builtin_amdgcn_s_setprio(1);
#pragma unroll
    for (int ks = 0; ks < 2; ks++)
#pragma unroll
      for (int mf = 0; mf < 4; mf++)
#pragma unroll
        for (int nf = 0; nf < 4; nf++)
          acc[mf + 4][nf] = __builtin_amdgcn_mfma_f32_16x16x32_bf16(af[mf][ks], bf[nf][ks], acc[mf + 4][nf], 0, 0, 0);
    __builtin_amdgcn_s_setprio(0);
    __builtin_amdgcn_s_barrier();   // all waves' A-reads retired -> A(buf p) free
  }
#undef A_STAGE
#undef B_STAGE

  const int b = bm >> 2;
  const int iBase = (bm & 3) * 256;

  if (bn < 4) {
    u16* dst0 = (bn < 2) ? Qb : Kb;
    const int bnn = bn & 1;
#pragma unroll
    for (int mf = 0; mf < 8; mf++) {
      const int lmb = wm*128 + mf*16 + g*4;
#pragma unroll
      for (int nf = 0; nf < 4; nf++) {
        const int ln = wn*64 + nf*16 + c;
#pragma unroll
        for (int r = 0; r < 4; r++) {
          const int lm = lmb + r;
          *(u16*)(sm + lm*512 + ((ln*2) ^ ((lm & 7) << 4))) = f2b(acc[mf][nf][r]);
        }
      }
    }
    __builtin_amdgcn_s_barrier();
#pragma unroll
    for (int it = 0; it < 16; it++) {
      const int gid = it*512 + tid;
      const int lm2 = gid >> 5, gsub = gid & 31;
      bf16x8 v = *(const bf16x8*)(sm + lm2*512 + ((gsub*16) ^ ((lm2 & 7) << 4)));
      const int h = bnn*2 + (gsub >> 4);
      const int d0 = (gsub & 15) * 8;
      *(bf16x8*)(dst0 + ((size_t)(b*4 + h)*1024 + iBase + lm2)*128 + d0) = v;
    }
  } else if (bn < 6) {
#pragma unroll
    for (int mf = 0; mf < 8; mf++) {
      const int lmb = wm*128 + mf*16 + g*4;
#pragma unroll
      for (int nf = 0; nf < 4; nf++) {
        const int ln = wn*64 + nf*16 + c;
        u32 w0, w1;
        asm("v_cvt_pk_bf16_f32 %0, %1, %2" : "=v"(w0) : "v"(acc[mf][nf][0]), "v"(acc[mf][nf][1]));
        asm("v_cvt_pk_bf16_f32 %0, %1, %2" : "=v"(w1) : "v"(acc[mf][nf][2]), "v"(acc[mf][nf][3]));
        uint2 pk; pk.x = w0; pk.y = w1;
        *(uint2*)(sm + ln*512 + ((lmb*2) ^ ((c & 7) << 4))) = pk;
      }
    }
    __builtin_amdgcn_s_barrier();
#pragma unroll
    for (int it = 0; it < 16; it++) {
      const int gid = it*512 + tid;
      const int ln2 = gid >> 5, gsub = gid & 31;
      bf16x8 v = *(const bf16x8*)(sm + ln2*512 + ((gsub*16) ^ ((ln2 & 7) << 4)));
      const int q2 = (bn - 4)*256 + ln2;
      const int h = q2 >> 7, d = q2 & 127;
      *(bf16x8*)(Vt + ((size_t)(b*4 + h)*128 + d)*1024 + iBase + gsub*8) = v;
    }
  } else {
#pragma unroll
    for (int mf = 0; mf < 8; mf++) {
      const int lmb = wm*128 + mf*16 + g*4;
#pragma unroll
      for (int nf = 0; nf < 4; nf++) {
        const int q = (bn - 6)*256 + wn*64 + nf*16 + c;
        if (q < 252) {
          const int h = q / 63, r2 = q - h*63;
#pragma unroll
          for (int r = 0; r < 4; r++)
            RELW[(size_t)((b*4 + h)*1024 + iBase + lmb + r)*64 + r2] = acc[mf][nf][r];
        } else if (q < 504) {
          const int qq = q - 252;
          const int h = qq / 63, r2 = qq - h*63;
#pragma unroll
          for (int r = 0; r < 4; r++)
            RELH[(size_t)((b*4 + h)*1024 + iBase + lmb + r)*64 + r2] = acc[mf][nf][r];
        }
      }
    }
  }
}

// ---------------- fused flash attention, SWAPPED QK^T (R4/R5-proven form) ----------------
__global__ __launch_bounds__(256) void attn_fused(
    const u16* __restrict__ Qb, const u16* __restrict__ Kb, const u16* __restrict__ Vt,
    const float* __restrict__ RELW, const float* __restrict__ RELH,
    u16* __restrict__ AO)
{
  __shared__ char sm[73728];   // [p][Kt 16KB][Vts 16KB] x2, Pl 8KB
  char* const Pl = sm + 65536;
  const int tid = threadIdx.x;
  const int w = tid >> 6, l = tid & 63, g = l >> 4, c = l & 15;
  const int bh = blockIdx.x, qt = blockIdx.y;
  const int i0 = qt * 64;

  bf16x8 qf[4];
  {
    const char* qbase = (const char*)Qb + (size_t)(bh*1024 + i0 + w*16 + c) * 256;
#pragma unroll
    for (int s = 0; s < 4; s++) qf[s] = *(const bf16x8*)(qbase + s*64 + g*16);
  }

  const int i = i0 + w*16 + c;
  const int xi = i & 31, yi = i >> 5;
  const float* rw = RELW + ((size_t)(bh*1024 + i) << 6);
  const float* rhb = RELH + ((size_t)(bh*1024 + i) << 6) + (31 - yi);
  float xwh[2][4];
#pragma unroll
  for (int e = 0; e < 2; e++)
#pragma unroll
    for (int r = 0; r < 4; r++) xwh[e][r] = rw[e*16 + g*4 + r - xi + 31];

  f32x4 Oacc[8];
#pragma unroll
  for (int fd = 0; fd < 8; fd++) Oacc[fd] = f32x4{0.f, 0.f, 0.f, 0.f};
  float m_q = -INFINITY, l_q = 0.f;

#define A_STAGE(jt, p)                                                                     \
  {                                                                                        \
    char* Kt_ = sm + (p)*32768;                                                            \
    char* Vs_ = Kt_ + 16384;                                                               \
    const int j0b = (jt) * 64;                                                             \
    _Pragma("unroll")                                                                      \
    for (int t = 0; t < 4; t++) {                                                          \
      const int L = (w*4 + t)*1024 + l*16;                                                 \
      const int jr = L >> 8, jb = L & 255;                                                 \
      glds16((const char*)Kb + (size_t)(bh*1024 + j0b + jr) * 256 + (jb ^ ((jr & 7) << 4)),\
             Kt_ + L);                                                                     \
      const int dr = L >> 7, db = L & 127;                                                 \
      glds16((const char*)Vt + (size_t)(bh*128 + dr) * 2048 + j0b*2 + (db ^ ((dr & 7) << 4)),\
             Vs_ + L);                                                                     \
    }                                                                                      \
  }

  A_STAGE(0, 0);
  A_STAGE(1, 1);
  float yh0 = rhb[0], yh1 = rhb[1];

#pragma unroll 2
  for (int jt = 0; jt < 16; jt++) {
    const int p = jt & 1;
    if (jt < 15) { asm volatile("s_waitcnt vmcnt(8)" ::: "memory"); }
    else         { asm volatile("s_waitcnt vmcnt(0)" ::: "memory"); }
    __builtin_amdgcn_s_barrier();

    const char* Kt_ = sm + p*32768;
    const char* Vs_ = Kt_ + 16384;

    f32x4 acc[4];
#pragma unroll
    for (int fn = 0; fn < 4; fn++) acc[fn] = f32x4{0.f, 0.f, 0.f, 0.f};
    __builtin_amdgcn_s_setprio(1);
#pragma unroll
    for (int s = 0; s < 4; s++) {
      const int koff = (s*64 + g*16) ^ ((c & 7) << 4);
#pragma unroll
      for (int fn = 0; fn < 4; fn++) {
        bf16x8 kf = *(const bf16x8*)(Kt_ + (fn*16 + c)*256 + koff);
        acc[fn] = __builtin_amdgcn_mfma_f32_16x16x32_bf16(kf, qf[s], acc[fn], 0, 0, 0);
      }
    }
    __builtin_amdgcn_s_setprio(0);

#pragma unroll
    for (int fn = 0; fn < 4; fn++)
#pragma unroll
      for (int r = 0; r < 4; r++)
        acc[fn][r] += xwh[fn & 1][r] + ((fn >> 1) ? yh1 : yh0);

    float mx = fmaxf(fmaxf(fmaxf(acc[0][0], acc[0][1]), fmaxf(acc[0][2], acc[0][3])),
                     fmaxf(fmaxf(acc[1][0], acc[1][1]), fmaxf(acc[1][2], acc[1][3])));
    mx = fmaxf(mx, fmaxf(fmaxf(fmaxf(acc[2][0], acc[2][1]), fmaxf(acc[2][2], acc[2][3])),
                         fmaxf(fmaxf(acc[3][0], acc[3][1]), fmaxf(acc[3][2], acc[3][3]))));
    mx = fmaxf(mx, __shfl_xor(mx, 16));
    mx = fmaxf(mx, __shfl_xor(mx, 32));
    const float mnew = fmaxf(m_q, mx);
    const float scq = __expf(m_q - mnew);
    m_q = mnew;

    float pv[4][4];
    float ps = 0.f;
#pragma unroll
    for (int fn = 0; fn < 4; fn++) {
#pragma unroll
      for (int r = 0; r < 4; r++) {
        pv[fn][r] = __expf(acc[fn][r] - mnew);
        ps += pv[fn][r];
      }
    }
    ps += __shfl_xor(ps, 16);
    ps += __shfl_xor(ps, 32);
    l_q = l_q * scq + ps;

    float nyh0 = 0.f, nyh1 = 0.f;
    if (jt < 15) { nyh0 = rhb[(jt + 1)*2]; nyh1 = rhb[(jt + 1)*2 + 1]; }

    {
      char* pb = Pl + w*2048 + c*128;
      const int swz = (c & 7) << 4;
#pragma unroll
      for (int fn = 0; fn < 4; fn++) {
        u32 w0, w1;
        asm("v_cvt_pk_bf16_f32 %0, %1, %2" : "=v"(w0) : "v"(pv[fn][0]), "v"(pv[fn][1]));
        asm("v_cvt_pk_bf16_f32 %0, %1, %2" : "=v"(w1) : "v"(pv[fn][2]), "v"(pv[fn][3]));
        uint2 pk; pk.x = w0; pk.y = w1;
        *(uint2*)(pb + ((fn*32 + g*8) ^ swz)) = pk;
      }
    }

#pragma unroll
    for (int r = 0; r < 4; r++) {
      const float scr = __shfl(scq, g*4 + r, 16);
#pragma unroll
      for (int fd = 0; fd < 8; fd++) Oacc[fd][r] *= scr;
    }

    __builtin_amdgcn_s_setprio(1);
#pragma unroll
    for (int s = 0; s < 2; s++) {
      const int koff = (s*64 + g*16) ^ ((c & 7) << 4);
      bf16x8 pf = *(const bf16x8*)(Pl + w*2048 + c*128 + koff);
#pragma unroll
      for (int fd = 0; fd < 8; fd++) {
        bf16x8 vf = *(const bf16x8*)(Vs_ + (fd*16 + c)*128 + koff);
        Oacc[fd] = __builtin_amdgcn_mfma_f32_16x16x32_bf16(pf, vf, Oacc[fd], 0, 0, 0);
      }
    }
    __builtin_amdgcn_s_setprio(0);

    __builtin_amdgcn_s_barrier();
    if (jt < 14) A_STAGE(jt + 2, p);
    yh0 = nyh0; yh1 = nyh1;
  }

  const int b = bh >> 2, h = bh & 3;
#pragma unroll
  for (int r = 0; r < 4; r++) {
    const float lr = __shfl(l_q, g*4 + r, 16);
    const float linv = 1.0f / lr;
    const int io = i0 + w*16 + g*4 + r;
#pragma unroll
    for (int fd = 0; fd < 8; fd++) {
      AO[(size_t)(b*1024 + io)*512 + h*128 + fd*16 + c] = f2b(Oacc[fd][r] * linv);
    }
  }
#undef A_STAGE
}

// ---------------- output GEMM (128x128 tile, 4 waves, 2-deep pipeline; R5-proven) ----------
__global__ __launch_bounds__(256) void gemm_out(
    const u16* __restrict__ A, const u16* __restrict__ Bt, float* __restrict__ outF)
{
  __shared__ char sm[65536];
  const int tid = threadIdx.x;
  const int w = tid >> 6, l = tid & 63, g = l >> 4, c = l & 15;
  const int bm = blockIdx.x, bn = blockIdx.y;
  const int wm = (w >> 1) * 64, wn = (w & 1) * 64;

  f32x4 acc[4][4];
#pragma unroll
  for (int i = 0; i < 4; i++)
#pragma unroll
    for (int j = 0; j < 4; j++) acc[i][j] = f32x4{0.f, 0.f, 0.f, 0.f};

  const char* Ab = (const char*)A;
  const char* Bb = (const char*)Bt;
  const int rsub = l >> 3;
  const int csw = (((l & 7) ^ rsub) << 4);

#define G_STAGE(kb, p)                                                                    \
  {                                                                                       \
    char* As_ = sm + (p)*32768;                                                           \
    char* Bs_ = As_ + 16384;                                                              \
    const int kbyte = (kb) * 128;                                                         \
    _Pragma("unroll")                                                                     \
    for (int t = 0; t < 4; t++) {                                                         \
      const int row = (w*4 + t)*8 + rsub;                                                 \
      glds16(Ab + (size_t)(bm*128 + row) * 1024 + kbyte + csw, As_ + (w*4 + t)*1024);     \
      glds16(Bb + (size_t)(bn*128 + row) * 1024 + kbyte + csw, Bs_ + (w*4 + t)*1024);     \
    }                                                                                     \
  }

  G_STAGE(0, 0);
  G_STAGE(1, 1);

#pragma unroll
  for (int kb = 0; kb < 8; kb++) {
    const int p = kb & 1;
    if (kb < 7) { asm volatile("s_waitcnt vmcnt(8)" ::: "memory"); }
    else        { asm volatile("s_waitcnt vmcnt(0)" ::: "memory"); }
    __builtin_amdgcn_s_barrier();
    const char* As_ = sm + p*32768;
    const char* Bs_ = As_ + 16384;
#pragma unroll
    for (int ks = 0; ks < 2; ks++) {
      const int koff = (ks*64 + g*16) ^ ((c & 7) << 4);
      bf16x8 af[4], bfr[4];
#pragma unroll
      for (int mf = 0; mf < 4; mf++)
        af[mf] = *(const bf16x8*)(As_ + (wm + mf*16 + c)*128 + koff);
#pragma unroll
      for (int nf = 0; nf < 4; nf++)
        bfr[nf] = *(const bf16x8*)(Bs_ + (wn + nf*16 + c)*128 + koff);
#pragma unroll
      for (int mf = 0; mf < 4; mf++)
#pragma unroll
        for (int nf = 0; nf < 4; nf++)
          acc[mf][nf] = __builtin_amdgcn_mfma_f32_16x16x32_bf16(af[mf], bfr[nf], acc[mf][nf], 0, 0, 0);
    }
    __builtin_amdgcn_s_barrier();
    if (kb < 6) G_STAGE(kb + 2, p);
  }
#undef G_STAGE

#pragma unroll
  for (int mf = 0; mf < 4; mf++) {
#pragma unroll
    for (int nf = 0; nf < 4; nf++) {
      const int n = bn*128 + wn + nf*16 + c;
#pragma unroll
      for (int r = 0; r < 4; r++) {
        const int m = bm*128 + wm + mf*16 + g*4 + r;
        outF[(size_t)m*512 + n] = acc[mf][nf][r];
      }
    }
  }
}

// ---------------- launcher ----------------
extern "C" void kernel_launch(void* const* d_in, const int* in_sizes, int n_in,
                              void* d_out, int out_size, void* d_ws, size_t ws_size,
                              hipStream_t stream) {
  const float* x   = (const float*)d_in[0];
  const float* Wq  = (const float*)d_in[1];
  const float* Wk  = (const float*)d_in[2];
  const float* Wv  = (const float*)d_in[3];
  const float* Wo  = (const float*)d_in[4];
  const float* pew = (const float*)d_in[5];
  const float* peh = (const float*)d_in[6];

  char* ws = (char*)d_ws;
  u16* xb    = (u16*)ws;    ws += (size_t)8192*512*2;
  u16* WbigT = (u16*)ws;    ws += (size_t)2048*512*2;
  u16* WoT   = (u16*)ws;    ws += (size_t)512*512*2;
  u16* Qb    = (u16*)ws;    ws += (size_t)32*1024*128*2;
  u16* Kb    = (u16*)ws;    ws += (size_t)32*1024*128*2;
  u16* Vt    = (u16*)ws;    ws += (size_t)32*1024*128*2;
  float* RELW = (float*)ws; ws += (size_t)32*1024*64*4;
  float* RELH = (float*)ws; ws += (size_t)32*1024*64*4;
  u16* AO    = (u16*)ws;    ws += (size_t)8192*512*2;

  castx<<<4096, 256, 0, stream>>>(x, xb);
  buildw<<<2056, 256, 0, stream>>>(Wq, Wk, Wv, Wo, WbigT, WoT);
  wpe_kernel<<<512, 256, 0, stream>>>(Wq, pew, peh, WbigT);
  gemm256<<<dim3(32, 8), 512, 0, stream>>>(xb, WbigT, Qb, Kb, Vt, RELW, RELH);
  attn_fused<<<dim3(32, 16), 256, 0, stream>>>(Qb, Kb, Vt, RELW, RELH, AO);
  gemm_out<<<dim3(64, 4), 256, 0, stream>>>(AO, WoT, (float*)d_out);
}